// Round 1
// baseline (9.756 us; speedup 1.0000x reference)
//
#include <hip/hip_runtime.h>
#include <math.h>

#define NUM_STEPS   3
#define NUM_POINTS  16
#define IN_CH       64
#define OUT_CH      256

// One 64-lane wave per data row (64 in-channels). 256-thread block = 4 rows.
// Key algebraic simplification: the out-channel broadcast dimension (256) is
// fully redundant in the reference — every out-channel copy of x[n,c,:] is
// identical through all steps, so out[n, o] == sum_c x_final[n, c] for all o.
__global__ __launch_bounds__(256)
void flow_kernel(const float* __restrict__ data,
                 const float* __restrict__ angles,
                 const float* __restrict__ velo,
                 float* __restrict__ out,
                 int nrows) {
    __shared__ float s_vcos[NUM_POINTS];
    __shared__ float s_vsin[NUM_POINTS];

    const int tid = threadIdx.x;
    if (tid < NUM_POINTS) {
        const float a = angles[tid];
        const float v = velo[tid];
        s_vcos[tid] = v * cosf(a);   // v*cos(a): the t-independent term
        s_vsin[tid] = v * sinf(a);   // v*sin(a): multiplied by t
    }
    __syncthreads();

    const int lane = tid & 63;                       // in-channel index
    const int wave = tid >> 6;                       // row within block
    const int row  = blockIdx.x * (blockDim.x >> 6) + wave;
    if (row >= nrows) return;

    // coalesced: consecutive lanes read consecutive floats
    float x = data[row * IN_CH + lane];

#pragma unroll
    for (int s = 0; s < NUM_STEPS; ++s) {
        const float t = tanhf(x);
        // jnp.round == round-half-to-even == rintf (default rounding mode)
        int pos = (int)rintf((1.0f + t) * (NUM_POINTS * 0.5f));
        pos = min(max(pos, 0), NUM_POINTS - 1);
        const float st = s_vcos[pos] + t * s_vsin[pos];
        x += st / (float)NUM_STEPS;
    }

    // 64-lane butterfly reduction: every lane ends with the full row sum
#pragma unroll
    for (int off = 1; off < 64; off <<= 1) {
        x += __shfl_xor(x, off);
    }

    // broadcast-store: 256 identical floats per row; lane c writes float4 at
    // out[row*256 + 4*c] -> one fully-coalesced 1 KiB store per wave
    float4 v4 = make_float4(x, x, x, x);
    reinterpret_cast<float4*>(out + (size_t)row * OUT_CH)[lane] = v4;
}

extern "C" void kernel_launch(void* const* d_in, const int* in_sizes, int n_in,
                              void* d_out, int out_size, void* d_ws, size_t ws_size,
                              hipStream_t stream) {
    const float* data   = (const float*)d_in[0];
    const float* angles = (const float*)d_in[1];
    const float* velo   = (const float*)d_in[2];
    float* out = (float*)d_out;

    const int nrows = in_sizes[0] / IN_CH;           // 4096
    const int rows_per_block = 256 / 64;             // 4 rows per 256-thread block
    const int grid = (nrows + rows_per_block - 1) / rows_per_block;

    flow_kernel<<<grid, 256, 0, stream>>>(data, angles, velo, out, nrows);
}